// Round 11
// baseline (320.011 us; speedup 1.0000x reference)
//
#include <hip/hip_runtime.h>
#include <math.h>

#define BATCH 32
#define NC    1024
#define NHID  512
#define NH    56
#define NW    56
#define HWSZ  3136   // 56*56
#define HW4   784    // HWSZ/4 (= 56 rows * 14 float4/row)

typedef float nfloat4 __attribute__((ext_vector_type(4)));

__device__ __forceinline__ float gelu_exact(float x) {
    return 0.5f * x * (1.0f + erff(x * 0.7071067811865476f));
}

// ---------------------------------------------------------------------------
// Kernel 1: GAP. One WAVE per (b,c) row — no LDS, no barriers. NT loads.
// MEASURED R10: 59.8 us = 6.9 TB/s, at fill-rate. Do not touch.
// ---------------------------------------------------------------------------
__global__ __launch_bounds__(256) void gap_kernel(const float* __restrict__ x,
                                                  float* __restrict__ y) {
    const int row  = (blockIdx.x << 2) | (threadIdx.x >> 6); // 4 waves/block
    const int lane = threadIdx.x & 63;
    const nfloat4* xr = (const nfloat4*)(x + (size_t)row * HWSZ);

    float s = 0.f;
#pragma unroll
    for (int it = 0; it < 12; ++it) {
        nfloat4 v = __builtin_nontemporal_load(xr + lane + (it << 6));
        s += (v.x + v.y) + (v.z + v.w);
    }
    if (lane < 16) {
        nfloat4 v = __builtin_nontemporal_load(xr + 768 + lane);
        s += (v.x + v.y) + (v.z + v.w);
    }
#pragma unroll
    for (int off = 32; off > 0; off >>= 1) s += __shfl_down(s, off);
    if (lane == 0) y[row] = s * (1.0f / 3136.0f);
}

// ---------------------------------------------------------------------------
// Kernel 2: h = gelu(y @ W1). Block=(jc,b): 64 cols via 16 lanes x float4,
// 16-way split-K (64 c-iters/thread), float4 weight loads.
// ---------------------------------------------------------------------------
__global__ __launch_bounds__(256) void fc1_kernel(const float* __restrict__ y,
                                                  const float* __restrict__ W1,
                                                  float* __restrict__ h) {
    const int jc = blockIdx.x;   // 0..7
    const int b  = blockIdx.y;   // 0..31
    const int t  = threadIdx.x;

    __shared__ float sy[NC];
    __shared__ nfloat4 part[256];
    for (int i = t; i < NC; i += 256) sy[i] = y[b * NC + i];
    __syncthreads();

    const int lane4 = t & 15;
    const int j0 = jc * 64 + lane4 * 4;
    const int ks = (t >> 4) * 64;            // 16 K-slices of 64

    nfloat4 acc0 = {0.f, 0.f, 0.f, 0.f};
    nfloat4 acc1 = {0.f, 0.f, 0.f, 0.f};
    const float* wbase = W1 + (size_t)ks * NHID + j0;
#pragma unroll 8
    for (int c = 0; c < 64; c += 2) {
        nfloat4 w0 = *(const nfloat4*)(wbase + (size_t)(c + 0) * NHID);
        nfloat4 w1 = *(const nfloat4*)(wbase + (size_t)(c + 1) * NHID);
        acc0 += sy[ks + c + 0] * w0;
        acc1 += sy[ks + c + 1] * w1;
    }
    part[t] = acc0 + acc1;
    __syncthreads();
    if (t < 16) {
        nfloat4 s = part[t];
#pragma unroll
        for (int g = 1; g < 16; ++g) s += part[g * 16 + t];
        float* hp = h + b * NHID + jc * 64 + t * 4;
        hp[0] = gelu_exact(s.x);
        hp[1] = gelu_exact(s.y);
        hp[2] = gelu_exact(s.z);
        hp[3] = gelu_exact(s.w);
    }
}

// ---------------------------------------------------------------------------
// Kernel 3: yp = gelu(h @ W2). Block=(cc,b): 64 cols via 16 lanes x float4,
// 16-way split-K (32 c-iters/thread).
// ---------------------------------------------------------------------------
__global__ __launch_bounds__(256) void fc2_kernel(const float* __restrict__ h,
                                                  const float* __restrict__ W2,
                                                  float* __restrict__ yp) {
    const int cc = blockIdx.x;   // 0..15
    const int b  = blockIdx.y;
    const int t  = threadIdx.x;

    __shared__ float sh[NHID];
    __shared__ nfloat4 part[256];
    for (int i = t; i < NHID; i += 256) sh[i] = h[b * NHID + i];
    __syncthreads();

    const int lane4 = t & 15;
    const int c0 = cc * 64 + lane4 * 4;
    const int js = (t >> 4) * 32;            // 16 K-slices of 32

    nfloat4 acc0 = {0.f, 0.f, 0.f, 0.f};
    nfloat4 acc1 = {0.f, 0.f, 0.f, 0.f};
    const float* wbase = W2 + (size_t)js * NC + c0;
#pragma unroll 8
    for (int jj = 0; jj < 32; jj += 2) {
        nfloat4 w0 = *(const nfloat4*)(wbase + (size_t)(jj + 0) * NC);
        nfloat4 w1 = *(const nfloat4*)(wbase + (size_t)(jj + 1) * NC);
        acc0 += sh[js + jj + 0] * w0;
        acc1 += sh[js + jj + 1] * w1;
    }
    part[t] = acc0 + acc1;
    __syncthreads();
    if (t < 16) {
        nfloat4 s = part[t];
#pragma unroll
        for (int g = 1; g < 16; ++g) s += part[g * 16 + t];
        float* pp = yp + b * NC + cc * 64 + t * 4;
        pp[0] = gelu_exact(s.x);
        pp[1] = gelu_exact(s.y);
        pp[2] = gelu_exact(s.z);
        pp[3] = gelu_exact(s.w);
    }
}

// ---------------------------------------------------------------------------
// Kernel 4: A = yp@WA+bA, Bv = yp@WB+bB. 512 threads, 8-way split-K.
// AB[b][0..55]=A, AB[b][64..119]=Bv.
// ---------------------------------------------------------------------------
__global__ __launch_bounds__(512) void ab_kernel(
    const float* __restrict__ yp, const float* __restrict__ WA,
    const float* __restrict__ bA, const float* __restrict__ WB,
    const float* __restrict__ bB, float* __restrict__ AB) {
    const int b = blockIdx.x;
    const int t = threadIdx.x;

    __shared__ float sp[NC];
    __shared__ float partA[512];
    __shared__ float partB[512];
    for (int i = t; i < NC; i += 512) sp[i] = yp[b * NC + i];
    __syncthreads();

    const int i  = t & 63;
    const int ks = (t >> 6) * 128;           // 8 K-slices of 128
    float a0 = 0.f, a1 = 0.f, a2 = 0.f, a3 = 0.f;
    float b0 = 0.f, b1 = 0.f, b2 = 0.f, b3 = 0.f;
    if (i < NH) {
        const float* wa = WA + (size_t)ks * NH + i;
        const float* wb = WB + (size_t)ks * NW + i;
        for (int c = 0; c < 128; c += 4) {
            a0 += sp[ks + c + 0] * wa[(size_t)(c + 0) * NH];
            a1 += sp[ks + c + 1] * wa[(size_t)(c + 1) * NH];
            a2 += sp[ks + c + 2] * wa[(size_t)(c + 2) * NH];
            a3 += sp[ks + c + 3] * wa[(size_t)(c + 3) * NH];
            b0 += sp[ks + c + 0] * wb[(size_t)(c + 0) * NW];
            b1 += sp[ks + c + 1] * wb[(size_t)(c + 1) * NW];
            b2 += sp[ks + c + 2] * wb[(size_t)(c + 2) * NW];
            b3 += sp[ks + c + 3] * wb[(size_t)(c + 3) * NW];
        }
    }
    partA[t] = (a0 + a1) + (a2 + a3);
    partB[t] = (b0 + b1) + (b2 + b3);
    __syncthreads();
    if (t < NH) {
        float sa = bA[t], sb = bB[t];
#pragma unroll
        for (int g = 0; g < 8; ++g) {
            sa += partA[g * 64 + t];
            sb += partB[g * 64 + t];
        }
        AB[b * 128 + t] = sa;
        AB[b * 128 + 64 + t] = sb;
    }
}

// ---------------------------------------------------------------------------
// Kernel 5: out[b,ch,i,j] = sigmoid(A[b,i]*Bv[b,j]), 16 channels per block.
// A/B THIS ROUND: regular stores instead of nontemporal.
// ---------------------------------------------------------------------------
__global__ __launch_bounds__(256) void bcast_kernel(const float* __restrict__ AB,
                                                    float* __restrict__ out) {
    const int blk = blockIdx.x;      // 32 b * 64 chunks
    const int b = blk >> 6;
    const int cchunk = blk & 63;
    const int t = threadIdx.x;

    __shared__ float sA[NH];
    __shared__ float sB[NW];
    if (t < NH) sA[t] = AB[b * 128 + t];
    else if (t >= 64 && t < 64 + NW) sB[t - 64] = AB[b * 128 + t];
    __syncthreads();

    nfloat4 v[4];
#pragma unroll
    for (int it = 0; it < 4; ++it) {
        const int idx = t + it * 256;          // float4 index in the 784-map
        if (idx < HW4) {
            const int r  = idx / 14;
            const int cb = (idx - r * 14) * 4;
            const float a = sA[r];
            nfloat4 q;
            q.x = 1.0f / (1.0f + expf(-(a * sB[cb + 0])));
            q.y = 1.0f / (1.0f + expf(-(a * sB[cb + 1])));
            q.z = 1.0f / (1.0f + expf(-(a * sB[cb + 2])));
            q.w = 1.0f / (1.0f + expf(-(a * sB[cb + 3])));
            v[it] = q;
        }
    }

    const size_t base = ((size_t)b * NC + (size_t)cchunk * 16) * HW4; // float4 units
#pragma unroll
    for (int ch = 0; ch < 16; ++ch) {
        nfloat4* orow = (nfloat4*)out + base + (size_t)ch * HW4;
#pragma unroll
        for (int it = 0; it < 4; ++it) {
            const int idx = t + it * 256;
            if (idx < HW4) orow[idx] = v[it];   // regular store (A/B vs NT)
        }
    }
}

// ---------------------------------------------------------------------------
extern "C" void kernel_launch(void* const* d_in, const int* in_sizes, int n_in,
                              void* d_out, int out_size, void* d_ws, size_t ws_size,
                              hipStream_t stream) {
    const float* x  = (const float*)d_in[0];
    const float* W1 = (const float*)d_in[1];
    const float* W2 = (const float*)d_in[2];
    const float* WA = (const float*)d_in[3];
    const float* bA = (const float*)d_in[4];
    const float* WB = (const float*)d_in[5];
    const float* bB = (const float*)d_in[6];
    float* out = (float*)d_out;

    float* y  = (float*)d_ws;            // BATCH*NC floats; yp aliases y
    float* yp = y;
    float* h  = y + BATCH * NC;          // BATCH*NHID floats
    float* AB = h + BATCH * NHID;        // BATCH*128 floats

    gap_kernel<<<BATCH * NC / 4, 256, 0, stream>>>(x, y);
    fc1_kernel<<<dim3(NHID / 64, BATCH), 256, 0, stream>>>(y, W1, h);
    fc2_kernel<<<dim3(NC / 64, BATCH), 256, 0, stream>>>(h, W2, yp);
    ab_kernel<<<BATCH, 512, 0, stream>>>(yp, WA, bA, WB, bB, AB);
    // BISECT: bcast launched 3x (idempotent). Marginal = 2 x bcast duration.
    bcast_kernel<<<BATCH * (NC / 16), 256, 0, stream>>>(AB, out);
    bcast_kernel<<<BATCH * (NC / 16), 256, 0, stream>>>(AB, out);
    bcast_kernel<<<BATCH * (NC / 16), 256, 0, stream>>>(AB, out);
}

// Round 12
// 168.909 us; speedup vs baseline: 1.8946x; 1.8946x over previous
//
#include <hip/hip_runtime.h>
#include <math.h>

#define BATCH 32
#define NC    1024
#define NHID  512
#define NH    56
#define NW    56
#define HWSZ  3136   // 56*56
#define HW4   784    // HWSZ/4 (= 56 rows * 14 float4/row)
#define CHBLK 32     // channels per bcast block -> 1024 blocks

typedef float nfloat4 __attribute__((ext_vector_type(4)));

__device__ __forceinline__ float gelu_exact(float x) {
    return 0.5f * x * (1.0f + erff(x * 0.7071067811865476f));
}

// ---------------------------------------------------------------------------
// Kernel 1: GAP. One WAVE per (b,c) row — no LDS, no barriers. NT loads.
// MEASURED R10: 59.8 us = 6.9 TB/s, at fill-rate. Do not touch.
// ---------------------------------------------------------------------------
__global__ __launch_bounds__(256) void gap_kernel(const float* __restrict__ x,
                                                  float* __restrict__ y) {
    const int row  = (blockIdx.x << 2) | (threadIdx.x >> 6); // 4 waves/block
    const int lane = threadIdx.x & 63;
    const nfloat4* xr = (const nfloat4*)(x + (size_t)row * HWSZ);

    float s = 0.f;
#pragma unroll
    for (int it = 0; it < 12; ++it) {
        nfloat4 v = __builtin_nontemporal_load(xr + lane + (it << 6));
        s += (v.x + v.y) + (v.z + v.w);
    }
    if (lane < 16) {
        nfloat4 v = __builtin_nontemporal_load(xr + 768 + lane);
        s += (v.x + v.y) + (v.z + v.w);
    }
#pragma unroll
    for (int off = 32; off > 0; off >>= 1) s += __shfl_down(s, off);
    if (lane == 0) y[row] = s * (1.0f / 3136.0f);
}

// ---------------------------------------------------------------------------
// Kernel 2: h = gelu(y @ W1). Block=(jc,b): 64 cols via 16 lanes x float4,
// 16-way split-K (64 c-iters/thread), float4 weight loads.
// ---------------------------------------------------------------------------
__global__ __launch_bounds__(256) void fc1_kernel(const float* __restrict__ y,
                                                  const float* __restrict__ W1,
                                                  float* __restrict__ h) {
    const int jc = blockIdx.x;   // 0..7
    const int b  = blockIdx.y;   // 0..31
    const int t  = threadIdx.x;

    __shared__ float sy[NC];
    __shared__ nfloat4 part[256];
    for (int i = t; i < NC; i += 256) sy[i] = y[b * NC + i];
    __syncthreads();

    const int lane4 = t & 15;
    const int j0 = jc * 64 + lane4 * 4;
    const int ks = (t >> 4) * 64;            // 16 K-slices of 64

    nfloat4 acc0 = {0.f, 0.f, 0.f, 0.f};
    nfloat4 acc1 = {0.f, 0.f, 0.f, 0.f};
    const float* wbase = W1 + (size_t)ks * NHID + j0;
#pragma unroll 8
    for (int c = 0; c < 64; c += 2) {
        nfloat4 w0 = *(const nfloat4*)(wbase + (size_t)(c + 0) * NHID);
        nfloat4 w1 = *(const nfloat4*)(wbase + (size_t)(c + 1) * NHID);
        acc0 += sy[ks + c + 0] * w0;
        acc1 += sy[ks + c + 1] * w1;
    }
    part[t] = acc0 + acc1;
    __syncthreads();
    if (t < 16) {
        nfloat4 s = part[t];
#pragma unroll
        for (int g = 1; g < 16; ++g) s += part[g * 16 + t];
        float* hp = h + b * NHID + jc * 64 + t * 4;
        hp[0] = gelu_exact(s.x);
        hp[1] = gelu_exact(s.y);
        hp[2] = gelu_exact(s.z);
        hp[3] = gelu_exact(s.w);
    }
}

// ---------------------------------------------------------------------------
// Kernel 3: yp = gelu(h @ W2). Block=(cc,b): 64 cols via 16 lanes x float4,
// 16-way split-K (32 c-iters/thread).
// ---------------------------------------------------------------------------
__global__ __launch_bounds__(256) void fc2_kernel(const float* __restrict__ h,
                                                  const float* __restrict__ W2,
                                                  float* __restrict__ yp) {
    const int cc = blockIdx.x;   // 0..15
    const int b  = blockIdx.y;
    const int t  = threadIdx.x;

    __shared__ float sh[NHID];
    __shared__ nfloat4 part[256];
    for (int i = t; i < NHID; i += 256) sh[i] = h[b * NHID + i];
    __syncthreads();

    const int lane4 = t & 15;
    const int c0 = cc * 64 + lane4 * 4;
    const int js = (t >> 4) * 32;            // 16 K-slices of 32

    nfloat4 acc0 = {0.f, 0.f, 0.f, 0.f};
    nfloat4 acc1 = {0.f, 0.f, 0.f, 0.f};
    const float* wbase = W2 + (size_t)js * NC + c0;
#pragma unroll 8
    for (int jj = 0; jj < 32; jj += 2) {
        nfloat4 w0 = *(const nfloat4*)(wbase + (size_t)(jj + 0) * NC);
        nfloat4 w1 = *(const nfloat4*)(wbase + (size_t)(jj + 1) * NC);
        acc0 += sh[js + jj + 0] * w0;
        acc1 += sh[js + jj + 1] * w1;
    }
    part[t] = acc0 + acc1;
    __syncthreads();
    if (t < 16) {
        nfloat4 s = part[t];
#pragma unroll
        for (int g = 1; g < 16; ++g) s += part[g * 16 + t];
        float* pp = yp + b * NC + cc * 64 + t * 4;
        pp[0] = gelu_exact(s.x);
        pp[1] = gelu_exact(s.y);
        pp[2] = gelu_exact(s.z);
        pp[3] = gelu_exact(s.w);
    }
}

// ---------------------------------------------------------------------------
// Kernel 4: A = yp@WA+bA, Bv = yp@WB+bB. 512 threads, 8-way split-K.
// AB[b][0..55]=A, AB[b][64..119]=Bv.
// ---------------------------------------------------------------------------
__global__ __launch_bounds__(512) void ab_kernel(
    const float* __restrict__ yp, const float* __restrict__ WA,
    const float* __restrict__ bA, const float* __restrict__ WB,
    const float* __restrict__ bB, float* __restrict__ AB) {
    const int b = blockIdx.x;
    const int t = threadIdx.x;

    __shared__ float sp[NC];
    __shared__ float partA[512];
    __shared__ float partB[512];
    for (int i = t; i < NC; i += 512) sp[i] = yp[b * NC + i];
    __syncthreads();

    const int i  = t & 63;
    const int ks = (t >> 6) * 128;           // 8 K-slices of 128
    float a0 = 0.f, a1 = 0.f, a2 = 0.f, a3 = 0.f;
    float b0 = 0.f, b1 = 0.f, b2 = 0.f, b3 = 0.f;
    if (i < NH) {
        const float* wa = WA + (size_t)ks * NH + i;
        const float* wb = WB + (size_t)ks * NW + i;
        for (int c = 0; c < 128; c += 4) {
            a0 += sp[ks + c + 0] * wa[(size_t)(c + 0) * NH];
            a1 += sp[ks + c + 1] * wa[(size_t)(c + 1) * NH];
            a2 += sp[ks + c + 2] * wa[(size_t)(c + 2) * NH];
            a3 += sp[ks + c + 3] * wa[(size_t)(c + 3) * NH];
            b0 += sp[ks + c + 0] * wb[(size_t)(c + 0) * NW];
            b1 += sp[ks + c + 1] * wb[(size_t)(c + 1) * NW];
            b2 += sp[ks + c + 2] * wb[(size_t)(c + 2) * NW];
            b3 += sp[ks + c + 3] * wb[(size_t)(c + 3) * NW];
        }
    }
    partA[t] = (a0 + a1) + (a2 + a3);
    partB[t] = (b0 + b1) + (b2 + b3);
    __syncthreads();
    if (t < NH) {
        float sa = bA[t], sb = bB[t];
#pragma unroll
        for (int g = 0; g < 8; ++g) {
            sa += partA[g * 64 + t];
            sb += partB[g * 64 + t];
        }
        AB[b * 128 + t] = sa;
        AB[b * 128 + 64 + t] = sb;
    }
}

// ---------------------------------------------------------------------------
// Kernel 5: bcast, fill-shaped. Block = (b, 32-channel chunk) -> 1024 blocks.
// Phase 1: sigmoid map (784 float4) into LDS. Phase 2: flat monotonic store
// stream over the contiguous 400KB region: op[k] = smap[k % 784]. Dense 1KB
// per wave-instruction, no dead lanes, no per-channel branching.
// ---------------------------------------------------------------------------
__global__ __launch_bounds__(256) void bcast_kernel(const float* __restrict__ AB,
                                                    float* __restrict__ out) {
    const int blk = blockIdx.x;      // 32 b * 32 chunks
    const int b = blk >> 5;
    const int cchunk = blk & 31;
    const int t = threadIdx.x;

    __shared__ float sA[NH];
    __shared__ float sB[NW];
    __shared__ nfloat4 smap[HW4];    // 12544 B
    if (t < NH) sA[t] = AB[b * 128 + t];
    else if (t >= 64 && t < 64 + NW) sB[t - 64] = AB[b * 128 + t];
    __syncthreads();

    for (int idx = t; idx < HW4; idx += 256) {
        const int r  = idx / 14;
        const int cb = (idx - r * 14) * 4;
        const float a = sA[r];
        nfloat4 q;
        q.x = 1.0f / (1.0f + expf(-(a * sB[cb + 0])));
        q.y = 1.0f / (1.0f + expf(-(a * sB[cb + 1])));
        q.z = 1.0f / (1.0f + expf(-(a * sB[cb + 2])));
        q.w = 1.0f / (1.0f + expf(-(a * sB[cb + 3])));
        smap[idx] = q;
    }
    __syncthreads();

    const size_t base = ((size_t)b * NC + (size_t)cchunk * CHBLK) * HW4;
    nfloat4* op = (nfloat4*)out + base;
#pragma unroll 4
    for (int k = t; k < CHBLK * HW4; k += 256) {
        op[k] = smap[k % HW4];
    }
}

// ---------------------------------------------------------------------------
extern "C" void kernel_launch(void* const* d_in, const int* in_sizes, int n_in,
                              void* d_out, int out_size, void* d_ws, size_t ws_size,
                              hipStream_t stream) {
    const float* x  = (const float*)d_in[0];
    const float* W1 = (const float*)d_in[1];
    const float* W2 = (const float*)d_in[2];
    const float* WA = (const float*)d_in[3];
    const float* bA = (const float*)d_in[4];
    const float* WB = (const float*)d_in[5];
    const float* bB = (const float*)d_in[6];
    float* out = (float*)d_out;

    float* y  = (float*)d_ws;            // BATCH*NC floats; yp aliases y
    float* yp = y;
    float* h  = y + BATCH * NC;          // BATCH*NHID floats
    float* AB = h + BATCH * NHID;        // BATCH*128 floats

    gap_kernel<<<BATCH * NC / 4, 256, 0, stream>>>(x, y);
    fc1_kernel<<<dim3(NHID / 64, BATCH), 256, 0, stream>>>(y, W1, h);
    fc2_kernel<<<dim3(NC / 64, BATCH), 256, 0, stream>>>(h, W2, yp);
    ab_kernel<<<BATCH, 512, 0, stream>>>(yp, WA, bA, WB, bB, AB);
    bcast_kernel<<<BATCH * (NC / CHBLK), 256, 0, stream>>>(AB, out);
}

// Round 13
// 163.552 us; speedup vs baseline: 1.9566x; 1.0328x over previous
//
#include <hip/hip_runtime.h>
#include <math.h>

#define BATCH 32
#define NC    1024
#define NHID  512
#define NH    56
#define NW    56
#define HWSZ  3136   // 56*56
#define HW4   784    // HWSZ/4 (= 56 rows * 14 float4/row)

typedef float nfloat4 __attribute__((ext_vector_type(4)));

__device__ __forceinline__ float gelu_exact(float x) {
    return 0.5f * x * (1.0f + erff(x * 0.7071067811865476f));
}

// ---------------------------------------------------------------------------
// Kernel 1: GAP (59.8 us = 6.9 TB/s, at fill-rate) + weight prefetch in the
// last 1152 blocks (4.6 MB -> L3) so the MLP chain hits L3 instead of HBM.
// ---------------------------------------------------------------------------
__global__ __launch_bounds__(256) void gap_kernel(const float* __restrict__ x,
                                                  float* __restrict__ y,
                                                  const float* __restrict__ W1,
                                                  const float* __restrict__ W2,
                                                  const float* __restrict__ WA,
                                                  const float* __restrict__ WB) {
    const int row  = (blockIdx.x << 2) | (threadIdx.x >> 6); // 4 waves/block
    const int lane = threadIdx.x & 63;
    const nfloat4* xr = (const nfloat4*)(x + (size_t)row * HWSZ);

    float s = 0.f;
#pragma unroll
    for (int it = 0; it < 12; ++it) {
        nfloat4 v = __builtin_nontemporal_load(xr + lane + (it << 6));
        s += (v.x + v.y) + (v.z + v.w);
    }
    if (lane < 16) {
        nfloat4 v = __builtin_nontemporal_load(xr + 768 + lane);
        s += (v.x + v.y) + (v.z + v.w);
    }
#pragma unroll
    for (int off = 32; off > 0; off >>= 1) s += __shfl_down(s, off);
    if (lane == 0) y[row] = s * (1.0f / 3136.0f);

    // ---- weight prefetch (late blocks so gap's streaming NT reads don't
    // evict it; one float4 per thread). W1: 131072 f4 (512 blk), W2: 131072
    // (512 blk), WA/WB: 14336 each (56 blk each). ----
    const int pb = (int)blockIdx.x - (BATCH * NC / 4 - 1152);
    if (pb >= 0) {
        const int t = threadIdx.x;
        float sink = 0.f;
        if (pb < 512) {
            nfloat4 w = ((const nfloat4*)W1)[pb * 256 + t];
            sink = w.x + w.w;
        } else if (pb < 1024) {
            nfloat4 w = ((const nfloat4*)W2)[(pb - 512) * 256 + t];
            sink = w.x + w.w;
        } else {
            const int q = pb - 1024;  // 0..127
            if (q < 56) {
                nfloat4 w = ((const nfloat4*)WA)[q * 256 + t];
                sink = w.x;
            } else if (q < 112) {
                nfloat4 w = ((const nfloat4*)WB)[(q - 56) * 256 + t];
                sink = w.x;
            }
        }
        asm volatile("" :: "v"(sink));  // keep the loads alive
    }
}

// ---------------------------------------------------------------------------
// Kernel 2: h = gelu(y @ W1). Grid (16,32)=512 blocks: 32 cols/block via
// 8 lanes x float4, 32-way split-K (32 float4 loads/thread, unroll 8).
// ---------------------------------------------------------------------------
__global__ __launch_bounds__(256) void fc1_kernel(const float* __restrict__ y,
                                                  const float* __restrict__ W1,
                                                  float* __restrict__ h) {
    const int jc = blockIdx.x;   // 0..15
    const int b  = blockIdx.y;   // 0..31
    const int t  = threadIdx.x;

    __shared__ float   sy[NC];
    __shared__ nfloat4 part[256];
    __shared__ nfloat4 spart[64];
    for (int i = t; i < NC; i += 256) sy[i] = y[b * NC + i];
    __syncthreads();

    const int lane8 = t & 7;
    const int j0 = jc * 32 + lane8 * 4;
    const int ks = (t >> 3) * 32;            // 32 K-slices of 32 rows

    nfloat4 acc0 = {0.f, 0.f, 0.f, 0.f};
    nfloat4 acc1 = {0.f, 0.f, 0.f, 0.f};
    const float* wbase = W1 + (size_t)ks * NHID + j0;
#pragma unroll 8
    for (int c = 0; c < 32; c += 2) {
        nfloat4 w0 = *(const nfloat4*)(wbase + (size_t)(c + 0) * NHID);
        nfloat4 w1 = *(const nfloat4*)(wbase + (size_t)(c + 1) * NHID);
        acc0 += sy[ks + c + 0] * w0;
        acc1 += sy[ks + c + 1] * w1;
    }
    part[t] = acc0 + acc1;
    __syncthreads();
    if (t < 64) spart[t] = part[t] + part[t + 64] + part[t + 128] + part[t + 192];
    __syncthreads();
    if (t < 8) {
        nfloat4 s = spart[t];
#pragma unroll
        for (int g = 1; g < 8; ++g) s += spart[g * 8 + t];
        float* hp = h + b * NHID + jc * 32 + t * 4;
        hp[0] = gelu_exact(s.x);
        hp[1] = gelu_exact(s.y);
        hp[2] = gelu_exact(s.z);
        hp[3] = gelu_exact(s.w);
    }
}

// ---------------------------------------------------------------------------
// Kernel 3: yp = gelu(h @ W2). Grid (32,32)=1024 blocks: 32 cols/block,
// 32-way split-K (16 float4 loads/thread).
// ---------------------------------------------------------------------------
__global__ __launch_bounds__(256) void fc2_kernel(const float* __restrict__ h,
                                                  const float* __restrict__ W2,
                                                  float* __restrict__ yp) {
    const int cc = blockIdx.x;   // 0..31
    const int b  = blockIdx.y;
    const int t  = threadIdx.x;

    __shared__ float   sh[NHID];
    __shared__ nfloat4 part[256];
    __shared__ nfloat4 spart[64];
    for (int i = t; i < NHID; i += 256) sh[i] = h[b * NHID + i];
    __syncthreads();

    const int lane8 = t & 7;
    const int c0 = cc * 32 + lane8 * 4;
    const int js = (t >> 3) * 16;            // 32 K-slices of 16 rows

    nfloat4 acc0 = {0.f, 0.f, 0.f, 0.f};
    nfloat4 acc1 = {0.f, 0.f, 0.f, 0.f};
    const float* wbase = W2 + (size_t)js * NC + c0;
#pragma unroll 8
    for (int jj = 0; jj < 16; jj += 2) {
        nfloat4 w0 = *(const nfloat4*)(wbase + (size_t)(jj + 0) * NC);
        nfloat4 w1 = *(const nfloat4*)(wbase + (size_t)(jj + 1) * NC);
        acc0 += sh[js + jj + 0] * w0;
        acc1 += sh[js + jj + 1] * w1;
    }
    part[t] = acc0 + acc1;
    __syncthreads();
    if (t < 64) spart[t] = part[t] + part[t + 64] + part[t + 128] + part[t + 192];
    __syncthreads();
    if (t < 8) {
        nfloat4 s = spart[t];
#pragma unroll
        for (int g = 1; g < 8; ++g) s += spart[g * 8 + t];
        float* pp = yp + b * NC + cc * 32 + t * 4;
        pp[0] = gelu_exact(s.x);
        pp[1] = gelu_exact(s.y);
        pp[2] = gelu_exact(s.z);
        pp[3] = gelu_exact(s.w);
    }
}

// ---------------------------------------------------------------------------
// Kernel 4: A = yp@WA+bA, Bv = yp@WB+bB. 512 thr = 32 groups of 16 lanes;
// group g handles K-rows [g*32, g*32+32) for BOTH A and B with float4
// weight loads (row = 14 float4). Dual accumulation streams for ILP.
// ---------------------------------------------------------------------------
__global__ __launch_bounds__(512) void ab_kernel(
    const float* __restrict__ yp, const float* __restrict__ WA,
    const float* __restrict__ bA, const float* __restrict__ WB,
    const float* __restrict__ bB, float* __restrict__ AB) {
    const int b = blockIdx.x;
    const int t = threadIdx.x;

    __shared__ float   sp[NC];
    __shared__ nfloat4 partA[512];
    __shared__ nfloat4 partB[512];
    for (int i = t; i < NC; i += 512) sp[i] = yp[b * NC + i];
    __syncthreads();

    const int grp    = t >> 4;     // 0..31
    const int lane16 = t & 15;     // 0..15 (active if < 14)
    const int ks     = grp * 32;
    nfloat4 accA = {0.f, 0.f, 0.f, 0.f};
    nfloat4 accB = {0.f, 0.f, 0.f, 0.f};
    if (lane16 < 14) {
        const nfloat4* wa = (const nfloat4*)WA + (size_t)ks * 14 + lane16;
        const nfloat4* wb = (const nfloat4*)WB + (size_t)ks * 14 + lane16;
#pragma unroll 8
        for (int c = 0; c < 32; ++c) {
            const float sv = sp[ks + c];
            accA += sv * wa[(size_t)c * 14];
            accB += sv * wb[(size_t)c * 14];
        }
    }
    partA[t] = accA;
    partB[t] = accB;
    __syncthreads();
    if (t < 16) {
        nfloat4 s = partA[t];
#pragma unroll
        for (int g = 1; g < 32; ++g) s += partA[g * 16 + t];
        if (t < 14) {
            const int i0 = t * 4;
            AB[b * 128 + i0 + 0] = bA[i0 + 0] + s.x;
            AB[b * 128 + i0 + 1] = bA[i0 + 1] + s.y;
            AB[b * 128 + i0 + 2] = bA[i0 + 2] + s.z;
            AB[b * 128 + i0 + 3] = bA[i0 + 3] + s.w;
        }
    } else if (t < 32) {
        const int l = t - 16;
        nfloat4 s = partB[l];
#pragma unroll
        for (int g = 1; g < 32; ++g) s += partB[g * 16 + l];
        if (l < 14) {
            const int i0 = l * 4;
            AB[b * 128 + 64 + i0 + 0] = bB[i0 + 0] + s.x;
            AB[b * 128 + 64 + i0 + 1] = bB[i0 + 1] + s.y;
            AB[b * 128 + 64 + i0 + 2] = bB[i0 + 2] + s.z;
            AB[b * 128 + 64 + i0 + 3] = bB[i0 + 3] + s.w;
        }
    }
}

// ---------------------------------------------------------------------------
// Kernel 5: bcast (R8 form — register-resident map, 16 ch/block, NT stores).
// MEASURED: ~79 us; three store shapes all land 79-85, treat as ceiling.
// ---------------------------------------------------------------------------
__global__ __launch_bounds__(256) void bcast_kernel(const float* __restrict__ AB,
                                                    float* __restrict__ out) {
    const int blk = blockIdx.x;      // 32 b * 64 chunks
    const int b = blk >> 6;
    const int cchunk = blk & 63;
    const int t = threadIdx.x;

    __shared__ float sA[NH];
    __shared__ float sB[NW];
    if (t < NH) sA[t] = AB[b * 128 + t];
    else if (t >= 64 && t < 64 + NW) sB[t - 64] = AB[b * 128 + t];
    __syncthreads();

    nfloat4 v[4];
#pragma unroll
    for (int it = 0; it < 4; ++it) {
        const int idx = t + it * 256;          // float4 index in the 784-map
        if (idx < HW4) {
            const int r  = idx / 14;
            const int cb = (idx - r * 14) * 4;
            const float a = sA[r];
            nfloat4 q;
            q.x = 1.0f / (1.0f + expf(-(a * sB[cb + 0])));
            q.y = 1.0f / (1.0f + expf(-(a * sB[cb + 1])));
            q.z = 1.0f / (1.0f + expf(-(a * sB[cb + 2])));
            q.w = 1.0f / (1.0f + expf(-(a * sB[cb + 3])));
            v[it] = q;
        }
    }

    const size_t base = ((size_t)b * NC + (size_t)cchunk * 16) * HW4; // float4 units
#pragma unroll
    for (int ch = 0; ch < 16; ++ch) {
        nfloat4* orow = (nfloat4*)out + base + (size_t)ch * HW4;
#pragma unroll
        for (int it = 0; it < 4; ++it) {
            const int idx = t + it * 256;
            if (idx < HW4) __builtin_nontemporal_store(v[it], &orow[idx]);
        }
    }
}

// ---------------------------------------------------------------------------
extern "C" void kernel_launch(void* const* d_in, const int* in_sizes, int n_in,
                              void* d_out, int out_size, void* d_ws, size_t ws_size,
                              hipStream_t stream) {
    const float* x  = (const float*)d_in[0];
    const float* W1 = (const float*)d_in[1];
    const float* W2 = (const float*)d_in[2];
    const float* WA = (const float*)d_in[3];
    const float* bA = (const float*)d_in[4];
    const float* WB = (const float*)d_in[5];
    const float* bB = (const float*)d_in[6];
    float* out = (float*)d_out;

    float* y  = (float*)d_ws;            // BATCH*NC floats; yp aliases y
    float* yp = y;
    float* h  = y + BATCH * NC;          // BATCH*NHID floats
    float* AB = h + BATCH * NHID;        // BATCH*128 floats

    gap_kernel<<<BATCH * NC / 4, 256, 0, stream>>>(x, y, W1, W2, WA, WB);
    fc1_kernel<<<dim3(NHID / 32, BATCH), 256, 0, stream>>>(y, W1, h);
    fc2_kernel<<<dim3(NC / 32, BATCH), 256, 0, stream>>>(h, W2, yp);
    ab_kernel<<<BATCH, 512, 0, stream>>>(yp, WA, bA, WB, bB, AB);
    bcast_kernel<<<BATCH * (NC / 16), 256, 0, stream>>>(AB, out);
}

// Round 14
// 162.137 us; speedup vs baseline: 1.9737x; 1.0087x over previous
//
#include <hip/hip_runtime.h>
#include <math.h>

#define BATCH 32
#define NC    1024
#define NHID  512
#define NH    56
#define NW    56
#define HWSZ  3136   // 56*56
#define HW4   784    // HWSZ/4 (= 56 rows * 14 float4/row)

typedef float nfloat4 __attribute__((ext_vector_type(4)));

__device__ __forceinline__ float gelu_exact(float x) {
    return 0.5f * x * (1.0f + erff(x * 0.7071067811865476f));
}

// ---------------------------------------------------------------------------
// Kernel 1: GAP. One WAVE per (b,c) row. MEASURED R10: 59.8 us = 6.9 TB/s,
// at fill-rate ceiling. Do not touch.
// ---------------------------------------------------------------------------
__global__ __launch_bounds__(256) void gap_kernel(const float* __restrict__ x,
                                                  float* __restrict__ y) {
    const int row  = (blockIdx.x << 2) | (threadIdx.x >> 6); // 4 waves/block
    const int lane = threadIdx.x & 63;
    const nfloat4* xr = (const nfloat4*)(x + (size_t)row * HWSZ);

    float s = 0.f;
#pragma unroll
    for (int it = 0; it < 12; ++it) {
        nfloat4 v = __builtin_nontemporal_load(xr + lane + (it << 6));
        s += (v.x + v.y) + (v.z + v.w);
    }
    if (lane < 16) {
        nfloat4 v = __builtin_nontemporal_load(xr + 768 + lane);
        s += (v.x + v.y) + (v.z + v.w);
    }
#pragma unroll
    for (int off = 32; off > 0; off >>= 1) s += __shfl_down(s, off);
    if (lane == 0) y[row] = s * (1.0f / 3136.0f);
}

// ---------------------------------------------------------------------------
// Kernel 2: h = gelu(y @ W1). Grid (16,32)=512 blocks: 32 cols/block via
// 8 lanes x float4, 32-way split-K.
// ---------------------------------------------------------------------------
__global__ __launch_bounds__(256) void fc1_kernel(const float* __restrict__ y,
                                                  const float* __restrict__ W1,
                                                  float* __restrict__ h) {
    const int jc = blockIdx.x;   // 0..15
    const int b  = blockIdx.y;   // 0..31
    const int t  = threadIdx.x;

    __shared__ float   sy[NC];
    __shared__ nfloat4 part[256];
    __shared__ nfloat4 spart[64];
    for (int i = t; i < NC; i += 256) sy[i] = y[b * NC + i];
    __syncthreads();

    const int lane8 = t & 7;
    const int j0 = jc * 32 + lane8 * 4;
    const int ks = (t >> 3) * 32;            // 32 K-slices of 32 rows

    nfloat4 acc0 = {0.f, 0.f, 0.f, 0.f};
    nfloat4 acc1 = {0.f, 0.f, 0.f, 0.f};
    const float* wbase = W1 + (size_t)ks * NHID + j0;
#pragma unroll 8
    for (int c = 0; c < 32; c += 2) {
        nfloat4 w0 = *(const nfloat4*)(wbase + (size_t)(c + 0) * NHID);
        nfloat4 w1 = *(const nfloat4*)(wbase + (size_t)(c + 1) * NHID);
        acc0 += sy[ks + c + 0] * w0;
        acc1 += sy[ks + c + 1] * w1;
    }
    part[t] = acc0 + acc1;
    __syncthreads();
    if (t < 64) spart[t] = part[t] + part[t + 64] + part[t + 128] + part[t + 192];
    __syncthreads();
    if (t < 8) {
        nfloat4 s = spart[t];
#pragma unroll
        for (int g = 1; g < 8; ++g) s += spart[g * 8 + t];
        float* hp = h + b * NHID + jc * 32 + t * 4;
        hp[0] = gelu_exact(s.x);
        hp[1] = gelu_exact(s.y);
        hp[2] = gelu_exact(s.z);
        hp[3] = gelu_exact(s.w);
    }
}

// ---------------------------------------------------------------------------
// Kernel 3: yp = gelu(h @ W2). Grid (32,32)=1024 blocks: 32 cols/block,
// 32-way split-K.
// ---------------------------------------------------------------------------
__global__ __launch_bounds__(256) void fc2_kernel(const float* __restrict__ h,
                                                  const float* __restrict__ W2,
                                                  float* __restrict__ yp) {
    const int cc = blockIdx.x;   // 0..31
    const int b  = blockIdx.y;
    const int t  = threadIdx.x;

    __shared__ float   sh[NHID];
    __shared__ nfloat4 part[256];
    __shared__ nfloat4 spart[64];
    for (int i = t; i < NHID; i += 256) sh[i] = h[b * NHID + i];
    __syncthreads();

    const int lane8 = t & 7;
    const int c0 = cc * 32 + lane8 * 4;
    const int js = (t >> 3) * 16;            // 32 K-slices of 16 rows

    nfloat4 acc0 = {0.f, 0.f, 0.f, 0.f};
    nfloat4 acc1 = {0.f, 0.f, 0.f, 0.f};
    const float* wbase = W2 + (size_t)js * NC + c0;
#pragma unroll 8
    for (int jj = 0; jj < 16; jj += 2) {
        nfloat4 w0 = *(const nfloat4*)(wbase + (size_t)(jj + 0) * NC);
        nfloat4 w1 = *(const nfloat4*)(wbase + (size_t)(jj + 1) * NC);
        acc0 += sh[js + jj + 0] * w0;
        acc1 += sh[js + jj + 1] * w1;
    }
    part[t] = acc0 + acc1;
    __syncthreads();
    if (t < 64) spart[t] = part[t] + part[t + 64] + part[t + 128] + part[t + 192];
    __syncthreads();
    if (t < 8) {
        nfloat4 s = spart[t];
#pragma unroll
        for (int g = 1; g < 8; ++g) s += spart[g * 8 + t];
        float* pp = yp + b * NC + cc * 32 + t * 4;
        pp[0] = gelu_exact(s.x);
        pp[1] = gelu_exact(s.y);
        pp[2] = gelu_exact(s.z);
        pp[3] = gelu_exact(s.w);
    }
}

// ---------------------------------------------------------------------------
// Kernel 4: A = yp@WA+bA, Bv = yp@WB+bB. 512 thr = 32 groups of 16 lanes;
// float4 weight loads (row = 14 float4), dual A/B accumulation streams.
// ---------------------------------------------------------------------------
__global__ __launch_bounds__(512) void ab_kernel(
    const float* __restrict__ yp, const float* __restrict__ WA,
    const float* __restrict__ bA, const float* __restrict__ WB,
    const float* __restrict__ bB, float* __restrict__ AB) {
    const int b = blockIdx.x;
    const int t = threadIdx.x;

    __shared__ float   sp[NC];
    __shared__ nfloat4 partA[512];
    __shared__ nfloat4 partB[512];
    for (int i = t; i < NC; i += 512) sp[i] = yp[b * NC + i];
    __syncthreads();

    const int grp    = t >> 4;     // 0..31
    const int lane16 = t & 15;     // 0..15 (active if < 14)
    const int ks     = grp * 32;
    nfloat4 accA = {0.f, 0.f, 0.f, 0.f};
    nfloat4 accB = {0.f, 0.f, 0.f, 0.f};
    if (lane16 < 14) {
        const nfloat4* wa = (const nfloat4*)WA + (size_t)ks * 14 + lane16;
        const nfloat4* wb = (const nfloat4*)WB + (size_t)ks * 14 + lane16;
#pragma unroll 8
        for (int c = 0; c < 32; ++c) {
            const float sv = sp[ks + c];
            accA += sv * wa[(size_t)c * 14];
            accB += sv * wb[(size_t)c * 14];
        }
    }
    partA[t] = accA;
    partB[t] = accB;
    __syncthreads();
    if (t < 16) {
        nfloat4 s = partA[t];
#pragma unroll
        for (int g = 1; g < 32; ++g) s += partA[g * 16 + t];
        if (t < 14) {
            const int i0 = t * 4;
            AB[b * 128 + i0 + 0] = bA[i0 + 0] + s.x;
            AB[b * 128 + i0 + 1] = bA[i0 + 1] + s.y;
            AB[b * 128 + i0 + 2] = bA[i0 + 2] + s.z;
            AB[b * 128 + i0 + 3] = bA[i0 + 3] + s.w;
        }
    } else if (t < 32) {
        const int l = t - 16;
        nfloat4 s = partB[l];
#pragma unroll
        for (int g = 1; g < 32; ++g) s += partB[g * 16 + l];
        if (l < 14) {
            const int i0 = l * 4;
            AB[b * 128 + 64 + i0 + 0] = bB[i0 + 0] + s.x;
            AB[b * 128 + 64 + i0 + 1] = bB[i0 + 1] + s.y;
            AB[b * 128 + 64 + i0 + 2] = bB[i0 + 2] + s.z;
            AB[b * 128 + 64 + i0 + 3] = bB[i0 + 3] + s.w;
        }
    }
}

// ---------------------------------------------------------------------------
// Kernel 5: bcast v3 — WAVE-MONOTONIC stores. Block = (b, 16-ch chunk);
// wave w owns 4 consecutive channels = 3136 f4 = 49 instrs x 1KB, each
// instruction writing the NEXT 1KB (fill-shaped stream). Map in LDS with
// 64-entry wrap duplication so smap[pos+lane] never needs a modulo.
// ---------------------------------------------------------------------------
__global__ __launch_bounds__(256) void bcast_kernel(const float* __restrict__ AB,
                                                    float* __restrict__ out) {
    const int blk = blockIdx.x;      // 32 b * 64 chunks = 2048
    const int b = blk >> 6;
    const int cchunk = blk & 63;
    const int t = threadIdx.x;

    __shared__ float sA[NH];
    __shared__ float sB[NW];
    __shared__ nfloat4 smap[HW4 + 64];   // 848 entries, 13.3 KB
    if (t < NH) sA[t] = AB[b * 128 + t];
    else if (t >= 64 && t < 64 + NW) sB[t - 64] = AB[b * 128 + t];
    __syncthreads();

    for (int idx = t; idx < HW4 + 64; idx += 256) {
        const int p  = (idx >= HW4) ? idx - HW4 : idx;
        const int r  = p / 14;
        const int cb = (p - r * 14) * 4;
        const float a = sA[r];
        nfloat4 q;
        q.x = 1.0f / (1.0f + expf(-(a * sB[cb + 0])));
        q.y = 1.0f / (1.0f + expf(-(a * sB[cb + 1])));
        q.z = 1.0f / (1.0f + expf(-(a * sB[cb + 2])));
        q.w = 1.0f / (1.0f + expf(-(a * sB[cb + 3])));
        smap[idx] = q;
    }
    __syncthreads();

    const int w    = t >> 6;         // wave 0..3 -> 4 channels each
    const int lane = t & 63;
    nfloat4* op = (nfloat4*)out +
                  ((size_t)b * NC + (size_t)cchunk * 16 + (size_t)w * 4) * HW4;
    int pos = 0;                      // (it*64) % 784; max 768, +63 <= 831
#pragma unroll 7
    for (int it = 0; it < 49; ++it) {
        __builtin_nontemporal_store(smap[pos + lane], &op[it * 64 + lane]);
        pos += 64;
        if (pos >= HW4) pos -= HW4;
    }
}

// ---------------------------------------------------------------------------
extern "C" void kernel_launch(void* const* d_in, const int* in_sizes, int n_in,
                              void* d_out, int out_size, void* d_ws, size_t ws_size,
                              hipStream_t stream) {
    const float* x  = (const float*)d_in[0];
    const float* W1 = (const float*)d_in[1];
    const float* W2 = (const float*)d_in[2];
    const float* WA = (const float*)d_in[3];
    const float* bA = (const float*)d_in[4];
    const float* WB = (const float*)d_in[5];
    const float* bB = (const float*)d_in[6];
    float* out = (float*)d_out;

    float* y  = (float*)d_ws;            // BATCH*NC floats; yp aliases y
    float* yp = y;
    float* h  = y + BATCH * NC;          // BATCH*NHID floats
    float* AB = h + BATCH * NHID;        // BATCH*128 floats

    gap_kernel<<<BATCH * NC / 4, 256, 0, stream>>>(x, y);
    fc1_kernel<<<dim3(NHID / 32, BATCH), 256, 0, stream>>>(y, W1, h);
    fc2_kernel<<<dim3(NC / 32, BATCH), 256, 0, stream>>>(h, W2, yp);
    ab_kernel<<<BATCH, 512, 0, stream>>>(yp, WA, bA, WB, bB, AB);
    bcast_kernel<<<BATCH * (NC / 16), 256, 0, stream>>>(AB, out);
}